// Round 7
// baseline (263.561 us; speedup 1.0000x reference)
//
#include <hip/hip_runtime.h>
#include <hip/hip_bf16.h>

typedef unsigned short ush;
typedef __bf16 v8bf __attribute__((ext_vector_type(8)));
typedef float f32x4 __attribute__((ext_vector_type(4)));
typedef float f32x16 __attribute__((ext_vector_type(16)));

#define SPD 56           // input spatial dim
#define OSD 52           // output spatial dim
#define SP3 175616       // 56^3
#define N_A_ELEMS (2*125*64*32)   // 512000 (+2048 zero pad appended)
#define NCX 5488         // conv_x blocks: 2744 spatial-chunks x 2 cg
#define NBA 2008         // build_A blocks: 514048/256

// ---------------- kernel 1: fused aux — conv_x transpose + build_A ---------------------
__global__ void aux_kernel(const float* __restrict__ x, ush* __restrict__ xb,
                           const float* __restrict__ weight, const float* __restrict__ w_sc0,
                           const float* __restrict__ w_sc1, ush* __restrict__ A) {
    __shared__ float t[64 * 33];
    const int bid = blockIdx.x;
    const int tid = threadIdx.x;
    if (bid < NCX) {
        // ---- conv_x: x fp32 [c64][s] -> bf16 [cg2][s][c32] via LDS transpose ----
        const int s0 = (bid % 2744) * 64;
        const int cg = bid / 2744;
        const int w = tid >> 6, l = tid & 63;
        #pragma unroll
        for (int k = 0; k < 8; k++) {
            int c = w * 8 + k;
            t[l * 33 + c] = x[(cg * 32 + c) * SP3 + s0 + l];
        }
        __syncthreads();
        int v = tid >> 2, qq = tid & 3;
        union { ush u[8]; uint4 q4; } pk;
        #pragma unroll
        for (int j = 0; j < 8; j++) {
            __hip_bfloat16 b = __float2bfloat16(t[v * 33 + qq * 8 + j]);
            pk.u[j] = *(ush*)&b;
        }
        *(uint4*)(xb + ((size_t)(cg * SP3 + s0 + v)) * 32 + qq * 8) = pk.q4;
        return;
    }
    // ---- build_A: A[cg][tau][o][c] bf16, zero slice at tap index 250 ----
    int f = (bid - NCX) * 256 + tid;
    if (f >= N_A_ELEMS) {
        if (f < N_A_ELEMS + 2048) A[f] = 0;
        return;
    }
    int c   = f & 31;
    int o   = (f >> 5) & 63;
    int t2  = f >> 11;
    int tau = t2 % 125;
    int cg  = t2 / 125;
    int i   = cg * 32 + c;
    int dz = tau / 25, dy = (tau / 5) % 5, dx = tau % 5;
    float rz = -1.f + 0.5f * dz, ry = -1.f + 0.5f * dy, rx = -1.f + 0.5f * dx;
    float d = sqrtf(rz * rz + ry * ry + rx * rx);
    float dm = fmaxf(d, 1e-12f);
    float nv[3] = { rz / dm, ry / dm, rx / dm };
    float emb[5];
    #pragma unroll
    for (int m = 0; m < 5; m++) {
        float diff = 4.f * d - (float)m;
        float ta = diff + 1.f, tb = 1.f - diff;
        float sa = ta > 0.f ? expf(-1.f / ta) : 0.f;
        float sb = tb > 0.f ? expf(-1.f / tb) : 0.f;
        emb[m] = 1.14136f * 7.3890560989306495f * sa * sb;
    }
    const float PW0 = 0.17677669529663687f;
    const float PW1 = 0.30618621784789724f;
    const float IS3 = 0.57735026918962576f;
    float val = 0.f;
    int widx = -1; float scale = 0.f;
    if (i < 16) {
        if (o < 16) { widx = i * 16 + o;                         scale = PW0; }
        else        { int wc = (o - 16) / 3, kc = (o - 16) % 3;
                      widx = 256 + i * 16 + wc;                  scale = PW1 * nv[kc]; }
    } else {
        int u = (i - 16) / 3, ic = (i - 16) % 3;
        if (o < 16) { widx = 768 + u * 16 + o;                   scale = PW0 * nv[ic]; }
        else        { int wc = (o - 16) / 3, jc = (o - 16) % 3;
                      if (ic == jc) { widx = 512 + u * 16 + wc;  scale = PW1 * IS3; } }
    }
    if (widx >= 0) {
        float wv = 0.f;
        #pragma unroll
        for (int m = 0; m < 5; m++) wv += emb[m] * weight[m * 1024 + widx];
        val = scale * wv;
    }
    if (tau == 62) {
        if (i < 16 && o < 16) val += 0.25f * w_sc0[i * 16 + o];
        else if (i >= 16 && o >= 16) {
            int u = (i - 16) / 3, ic = (i - 16) % 3;
            int wc = (o - 16) / 3, jc = (o - 16) % 3;
            if (ic == jc) val += 0.25f * w_sc1[u * 16 + wc];
        }
    }
    __hip_bfloat16 b = __float2bfloat16(val);
    A[f] = *(ush*)&b;
}

// ---------------- kernel 2: main conv ---------------------------------------------------
// 1184 blocks (flat, XCD-swizzled) = 13x13x7 tiles; block 256 = 4 waves = (ns x ks).
// Wave (ns,ks): 64 oc x 64 px (n-tiles {2ns, 2ns+1}) x taps [ks*64,(ks+1)*64) per cg.
// acc = 4 x f32x16 = 64 AGPR -> 3 blocks/CU (3 waves/SIMD). 32x32x16 MFMA, flat K-loop.
// bz=6 overlaps z0=44 (rewrites z44..47 with identical values) -> no masking anywhere.
__launch_bounds__(256, 3)
__global__ void conv_main(const ush* __restrict__ A, const ush* __restrict__ xb,
                          float* __restrict__ out) {
    __shared__ ush patch[24576];   // 48 KB: staging 48 KB, epilogue red 32 KB overlay

    const int b  = blockIdx.x;
    const int bp = (b & 7) * 148 + (b >> 3);   // XCD-contiguous slab mapping
    if (bp >= 1183) return;
    const int bx = bp % 13;
    const int t1 = bp / 13;
    const int by = t1 % 13;
    const int bz = t1 / 13;                    // 0..6
    const int x0 = bx * 4, y0 = by * 4;
    const int z0 = (bz == 6) ? 44 : bz * 8;

    const int tid  = threadIdx.x;
    const int wv   = tid >> 6;
    const int ns   = wv & 1;                   // n-half
    const int ks   = wv >> 1;                  // k-half
    const int lane = tid & 63;
    const int lhi  = lane >> 5;                // k-subgroup for A/B operands
    // B col = lane&31 -> px (zloc = (l>>4)&1, y = (l>>2)&3, x = l&3)
    const int rbase32 = ((lane >> 4) & 1) * 64 + ((lane >> 2) & 3) * 8 + (lane & 3);
    const ush* Aw = A + (lane & 31) * 32 + lhi * 8;

    f32x16 acc[2][2];
    #pragma unroll
    for (int mt = 0; mt < 2; mt++)
        #pragma unroll
        for (int nt = 0; nt < 2; nt++)
            acc[mt][nt] = (f32x16)(0.f);

    for (int cg = 0; cg < 2; cg++) {
        __syncthreads();
        // stage this cg: 12 z-slices x 64 vox x 32ch = 3072 16B-chunks, swizzled
        #pragma unroll 4
        for (int it = 0; it < 12; it++) {
            int u   = tid + it * 256;
            int qq  = u & 3;
            int vox = u >> 2;
            int xp = vox & 7, yp = (vox >> 3) & 7, zp = vox >> 6;   // zp in [0,12)
            const ush* g = xb + ((size_t)((cg * SPD + z0 + zp) * SPD + (y0 + yp)) * SPD + (x0 + xp)) * 32 + qq * 8;
            uint4 v = *(const uint4*)g;
            int slot = vox * 4 + ((qq + vox + (vox >> 3)) & 3);
            *(uint4*)(patch + slot * 8) = v;
        }
        __syncthreads();

        // ---- K-half: wave handles taps [ks*64, ks*64+64); taps >=125 are zero-A ----
        const int t0 = ks * 64;
        int dz = t0 / 25; int rr = t0 - dz * 25; int dy = rr / 5; int dx = rr - dy * 5;

        #pragma unroll 2
        for (int j = 0; j < 64; j++) {
            int t = t0 + j;
            int vb = dz * 64 + dy * 8 + dx;
            if (vb > 292) vb = 0;                          // pad taps stay in-bounds
            int v0 = vb + rbase32;
            int pre = v0 + (v0 >> 3);
            int slot0 = v0 * 4 + ((lhi + pre) & 3);        // chunk h=0
            int slot1 = v0 * 4 + ((2 + lhi + pre) & 3);    // chunk h=1

            v8bf bf[2][2];
            #pragma unroll
            for (int nt = 0; nt < 2; nt++) {
                int off = (ns * 2 + nt) * 4096;
                bf[nt][0] = *(const v8bf*)(patch + slot0 * 8 + off);
                bf[nt][1] = *(const v8bf*)(patch + slot1 * 8 + off);
            }

            int toff = (t < 125) ? (cg * 125 + t) : 250;   // 250 -> zero slice
            v8bf af[2][2];
            #pragma unroll
            for (int mt = 0; mt < 2; mt++)
                #pragma unroll
                for (int h = 0; h < 2; h++)
                    af[mt][h] = *(const v8bf*)(Aw + (size_t)toff * 2048 + mt * 1024 + h * 16);

            #pragma unroll
            for (int h = 0; h < 2; h++)
                #pragma unroll
                for (int mt = 0; mt < 2; mt++)
                    #pragma unroll
                    for (int nt = 0; nt < 2; nt++)
                        acc[mt][nt] = __builtin_amdgcn_mfma_f32_32x32x16_bf16(af[mt][h], bf[nt][h], acc[mt][nt], 0, 0, 0);

            int c1 = (dx == 4);
            dx = c1 ? 0 : dx + 1;
            int c2 = c1 & (dy == 4);
            dy = c2 ? 0 : dy + c1;
            dz += c2;
        }
    }

    // ---- K-half reduction: ks=1 waves dump, ks=0 waves add + store ----
    __syncthreads();
    float* red = (float*)patch;                // red[ns][mt*2+nt][lane][16] = 32 KB
    if (ks == 1) {
        #pragma unroll
        for (int mt = 0; mt < 2; mt++)
            #pragma unroll
            for (int nt = 0; nt < 2; nt++) {
                float* p = red + ns * 4096 + (mt * 2 + nt) * 1024 + lane * 16;
                #pragma unroll
                for (int s = 0; s < 4; s++) {
                    f32x4 v = { acc[mt][nt][s*4+0], acc[mt][nt][s*4+1], acc[mt][nt][s*4+2], acc[mt][nt][s*4+3] };
                    *(f32x4*)(p + s * 4) = v;
                }
            }
    }
    __syncthreads();
    if (ks == 0) {
        const int yy = y0 + ((lane >> 2) & 3);
        const int xx = x0 + (lane & 3);
        #pragma unroll
        for (int mt = 0; mt < 2; mt++)
            #pragma unroll
            for (int nt = 0; nt < 2; nt++) {
                const float* p = red + ns * 4096 + (mt * 2 + nt) * 1024 + lane * 16;
                int zz = z0 + (ns * 2 + nt) * 2 + ((lane >> 4) & 1);
                #pragma unroll
                for (int s = 0; s < 4; s++) {
                    f32x4 v = *(const f32x4*)(p + s * 4);
                    f32x4 m = { acc[mt][nt][s*4+0], acc[mt][nt][s*4+1], acc[mt][nt][s*4+2], acc[mt][nt][s*4+3] };
                    v += m;
                    #pragma unroll
                    for (int e = 0; e < 4; e++) {
                        int o = mt * 32 + e + 8 * s + 4 * lhi;
                        out[((o * OSD + zz) * OSD + yy) * OSD + xx] = v[e];
                    }
                }
            }
    }
}

extern "C" void kernel_launch(void* const* d_in, const int* in_sizes, int n_in,
                              void* d_out, int out_size, void* d_ws, size_t ws_size,
                              hipStream_t stream) {
    const float* x      = (const float*)d_in[0];
    const float* weight = (const float*)d_in[1];
    const float* w_sc0  = (const float*)d_in[2];
    const float* w_sc1  = (const float*)d_in[3];
    float* out = (float*)d_out;

    ush* A  = (ush*)d_ws;                               // 514048 ush (incl. zero pad)
    ush* xb = (ush*)((char*)d_ws + (2 << 20));          // 22.5 MB

    aux_kernel<<<NCX + NBA, 256, 0, stream>>>(x, xb, weight, w_sc0, w_sc1, A);
    conv_main<<<1184, 256, 0, stream>>>(A, xb, out);
}

// Round 8
// 233.369 us; speedup vs baseline: 1.1294x; 1.1294x over previous
//
#include <hip/hip_runtime.h>
#include <hip/hip_bf16.h>

typedef unsigned short ush;
typedef __bf16 v8bf __attribute__((ext_vector_type(8)));
typedef float f32x4 __attribute__((ext_vector_type(4)));
typedef float f32x16 __attribute__((ext_vector_type(16)));

#define SPD 56           // input spatial dim
#define OSD 52           // output spatial dim
#define SP3 175616       // 56^3
#define N_A_ELEMS (2*125*64*32)   // 512000 (+2048 zero pad appended)
#define NCX 5488         // conv_x blocks: 2744 spatial-chunks x 2 cg
#define NBA 2008         // build_A blocks: 514048/256

// ---------------- kernel 1: fused aux — conv_x transpose + build_A ---------------------
__global__ void aux_kernel(const float* __restrict__ x, ush* __restrict__ xb,
                           const float* __restrict__ weight, const float* __restrict__ w_sc0,
                           const float* __restrict__ w_sc1, ush* __restrict__ A) {
    __shared__ float t[64 * 33];
    const int bid = blockIdx.x;
    const int tid = threadIdx.x;
    if (bid < NCX) {
        // ---- conv_x: x fp32 [c64][s] -> bf16 [cg2][s][c32] via LDS transpose ----
        const int s0 = (bid % 2744) * 64;
        const int cg = bid / 2744;
        const int w = tid >> 6, l = tid & 63;
        #pragma unroll
        for (int k = 0; k < 8; k++) {
            int c = w * 8 + k;
            t[l * 33 + c] = x[(cg * 32 + c) * SP3 + s0 + l];
        }
        __syncthreads();
        int v = tid >> 2, qq = tid & 3;
        union { ush u[8]; uint4 q4; } pk;
        #pragma unroll
        for (int j = 0; j < 8; j++) {
            __hip_bfloat16 b = __float2bfloat16(t[v * 33 + qq * 8 + j]);
            pk.u[j] = *(ush*)&b;
        }
        *(uint4*)(xb + ((size_t)(cg * SP3 + s0 + v)) * 32 + qq * 8) = pk.q4;
        return;
    }
    // ---- build_A: A[cg][tau][o][c] bf16, zero slice at tap index 250 ----
    int f = (bid - NCX) * 256 + tid;
    if (f >= N_A_ELEMS) {
        if (f < N_A_ELEMS + 2048) A[f] = 0;
        return;
    }
    int c   = f & 31;
    int o   = (f >> 5) & 63;
    int t2  = f >> 11;
    int tau = t2 % 125;
    int cg  = t2 / 125;
    int i   = cg * 32 + c;
    int dz = tau / 25, dy = (tau / 5) % 5, dx = tau % 5;
    float rz = -1.f + 0.5f * dz, ry = -1.f + 0.5f * dy, rx = -1.f + 0.5f * dx;
    float d = sqrtf(rz * rz + ry * ry + rx * rx);
    float dm = fmaxf(d, 1e-12f);
    float nv[3] = { rz / dm, ry / dm, rx / dm };
    float emb[5];
    #pragma unroll
    for (int m = 0; m < 5; m++) {
        float diff = 4.f * d - (float)m;
        float ta = diff + 1.f, tb = 1.f - diff;
        float sa = ta > 0.f ? expf(-1.f / ta) : 0.f;
        float sb = tb > 0.f ? expf(-1.f / tb) : 0.f;
        emb[m] = 1.14136f * 7.3890560989306495f * sa * sb;
    }
    const float PW0 = 0.17677669529663687f;
    const float PW1 = 0.30618621784789724f;
    const float IS3 = 0.57735026918962576f;
    float val = 0.f;
    int widx = -1; float scale = 0.f;
    if (i < 16) {
        if (o < 16) { widx = i * 16 + o;                         scale = PW0; }
        else        { int wc = (o - 16) / 3, kc = (o - 16) % 3;
                      widx = 256 + i * 16 + wc;                  scale = PW1 * nv[kc]; }
    } else {
        int u = (i - 16) / 3, ic = (i - 16) % 3;
        if (o < 16) { widx = 768 + u * 16 + o;                   scale = PW0 * nv[ic]; }
        else        { int wc = (o - 16) / 3, jc = (o - 16) % 3;
                      if (ic == jc) { widx = 512 + u * 16 + wc;  scale = PW1 * IS3; } }
    }
    if (widx >= 0) {
        float wv = 0.f;
        #pragma unroll
        for (int m = 0; m < 5; m++) wv += emb[m] * weight[m * 1024 + widx];
        val = scale * wv;
    }
    if (tau == 62) {
        if (i < 16 && o < 16) val += 0.25f * w_sc0[i * 16 + o];
        else if (i >= 16 && o >= 16) {
            int u = (i - 16) / 3, ic = (i - 16) % 3;
            int wc = (o - 16) / 3, jc = (o - 16) % 3;
            if (ic == jc) val += 0.25f * w_sc1[u * 16 + wc];
        }
    }
    __hip_bfloat16 b = __float2bfloat16(val);
    A[f] = *(ush*)&b;
}

// ---------------- kernel 2: main conv ---------------------------------------------------
// 1184 blocks (flat, XCD-swizzled) = 13x13x7 tiles; block 256 = 4 waves.
// Each wave: 64 oc x 128 px (4 n-tiles of 32 px = 2 z-slices each), 32x32x16 MFMA.
// K-split 128 taps (125 real + 3 zero-A) x 32/wave.
// Depth-1 software pipeline: A-fragments and B slot-addresses for tap t+1 are
// produced before tap t's MFMA block (512 cyc of cover for the L2 A-load latency).
// bz=6 overlaps z0=44 (rewrites z44..47 with identical values) -> no masking anywhere.
__launch_bounds__(256, 2)
__global__ void conv_main(const ush* __restrict__ A, const ush* __restrict__ xb,
                          float* __restrict__ out) {
    __shared__ ush patch[32768];   // 64 KB: staging 48 KB, epilogue red 64 KB

    const int b  = blockIdx.x;
    const int bp = (b & 7) * 148 + (b >> 3);   // XCD-contiguous slab mapping
    if (bp >= 1183) return;
    const int bx = bp % 13;
    const int t1 = bp / 13;
    const int by = t1 % 13;
    const int bz = t1 / 13;                    // 0..6
    const int x0 = bx * 4, y0 = by * 4;
    const int z0 = (bz == 6) ? 44 : bz * 8;

    const int tid  = threadIdx.x;
    const int wv   = tid >> 6;
    const int lane = tid & 63;
    const int lhi  = lane >> 5;                // k-group for A/B operands
    // B col = lane&31 -> px (zloc = (l>>4)&1, y = (l>>2)&3, x = l&3)
    const int rbase32 = ((lane >> 4) & 1) * 64 + ((lane >> 2) & 3) * 8 + (lane & 3);
    const ush* Aw = A + (lane & 31) * 32 + lhi * 8;

    f32x16 acc[2][4];
    #pragma unroll
    for (int mt = 0; mt < 2; mt++)
        #pragma unroll
        for (int nt = 0; nt < 4; nt++)
            acc[mt][nt] = (f32x16)(0.f);

    for (int cg = 0; cg < 2; cg++) {
        __syncthreads();
        // stage this cg: 12 z-slices x 64 vox x 32ch = 3072 16B-chunks, swizzled
        #pragma unroll 4
        for (int it = 0; it < 12; it++) {
            int u   = tid + it * 256;
            int qq  = u & 3;
            int vox = u >> 2;
            int xp = vox & 7, yp = (vox >> 3) & 7, zp = vox >> 6;   // zp in [0,12)
            const ush* g = xb + ((size_t)((cg * SPD + z0 + zp) * SPD + (y0 + yp)) * SPD + (x0 + xp)) * 32 + qq * 8;
            uint4 v = *(const uint4*)g;
            int slot = vox * 4 + ((qq + vox + (vox >> 3)) & 3);
            *(uint4*)(patch + slot * 8) = v;
        }
        __syncthreads();

        // ---- K-split: wave wv owns taps [wv*32, wv*32+32); taps >=125 are zero-A ----
        const int t0 = wv * 32;
        int dz = t0 / 25; int rr = t0 - dz * 25; int dy = rr / 5; int dx = rr - dy * 5;

        // prologue: slots + A-fragments for tap t0
        int vb = dz * 64 + dy * 8 + dx;
        int v0 = vb + rbase32;
        int pre = v0 + (v0 >> 3);
        int slot0c = v0 * 4 + ((lhi + pre) & 3);
        int slot1c = v0 * 4 + ((2 + lhi + pre) & 3);
        v8bf afc[2][2];
        {
            int toff = cg * 125 + t0;
            #pragma unroll
            for (int mt = 0; mt < 2; mt++)
                #pragma unroll
                for (int h = 0; h < 2; h++)
                    afc[mt][h] = *(const v8bf*)(Aw + (size_t)toff * 2048 + mt * 1024 + h * 16);
        }

        #pragma unroll 2
        for (int j = 0; j < 32; j++) {
            // B loads for tap j (addresses ready from previous iteration)
            v8bf bf[4][2];
            #pragma unroll
            for (int nt = 0; nt < 4; nt++) {
                bf[nt][0] = *(const v8bf*)(patch + slot0c * 8 + nt * 4096);
                bf[nt][1] = *(const v8bf*)(patch + slot1c * 8 + nt * 4096);
            }

            // decode + slot addresses for tap j+1
            int c1 = (dx == 4);
            dx = c1 ? 0 : dx + 1;
            int c2 = c1 & (dy == 4);
            dy = c2 ? 0 : dy + c1;
            dz += c2;
            int vbn = dz * 64 + dy * 8 + dx;
            if (vbn > 292) vbn = 0;                        // pad taps stay in-bounds
            int v1 = vbn + rbase32;
            int prn = v1 + (v1 >> 3);
            int slot0n = v1 * 4 + ((lhi + prn) & 3);
            int slot1n = v1 * 4 + ((2 + lhi + prn) & 3);

            // A prefetch for tap j+1 (always in-bounds: zero slice at 250)
            int tn = t0 + j + 1;
            int toffn = (tn < 125) ? (cg * 125 + tn) : 250;
            v8bf afn[2][2];
            #pragma unroll
            for (int mt = 0; mt < 2; mt++)
                #pragma unroll
                for (int h = 0; h < 2; h++)
                    afn[mt][h] = *(const v8bf*)(Aw + (size_t)toffn * 2048 + mt * 1024 + h * 16);

            // MFMA block for tap j (512 SIMD-cyc of cover for the prefetches above)
            #pragma unroll
            for (int h = 0; h < 2; h++)
                #pragma unroll
                for (int mt = 0; mt < 2; mt++)
                    #pragma unroll
                    for (int nt = 0; nt < 4; nt++)
                        acc[mt][nt] = __builtin_amdgcn_mfma_f32_32x32x16_bf16(afc[mt][h], bf[nt][h], acc[mt][nt], 0, 0, 0);

            // rotate pipeline registers
            #pragma unroll
            for (int mt = 0; mt < 2; mt++)
                #pragma unroll
                for (int h = 0; h < 2; h++)
                    afc[mt][h] = afn[mt][h];
            slot0c = slot0n;
            slot1c = slot1n;
        }
    }

    // ---- cross-wave reduction: red[writer][frag8][lane][16] = 64 KB ----
    __syncthreads();
    float* red = (float*)patch;
    if (wv >= 2) {
        #pragma unroll
        for (int mt = 0; mt < 2; mt++)
            #pragma unroll
            for (int nt = 0; nt < 4; nt++) {
                float* p = red + (wv - 2) * 8192 + (mt * 4 + nt) * 1024 + lane * 16;
                #pragma unroll
                for (int s = 0; s < 4; s++) {
                    f32x4 v = { acc[mt][nt][s*4+0], acc[mt][nt][s*4+1], acc[mt][nt][s*4+2], acc[mt][nt][s*4+3] };
                    *(f32x4*)(p + s * 4) = v;
                }
            }
    }
    __syncthreads();
    if (wv < 2) {
        #pragma unroll
        for (int mt = 0; mt < 2; mt++)
            #pragma unroll
            for (int nt = 0; nt < 4; nt++) {
                float* p = red + wv * 8192 + (mt * 4 + nt) * 1024 + lane * 16;
                #pragma unroll
                for (int s = 0; s < 4; s++) {
                    f32x4 v = *(const f32x4*)(p + s * 4);
                    f32x4 m = { acc[mt][nt][s*4+0], acc[mt][nt][s*4+1], acc[mt][nt][s*4+2], acc[mt][nt][s*4+3] };
                    *(f32x4*)(p + s * 4) = v + m;
                }
            }
    }
    __syncthreads();

    // store: 8 frags total; wave wv stores frags {2wv, 2wv+1}; final = half0 + half1
    const int yy = y0 + ((lane >> 2) & 3);
    const int xx = x0 + (lane & 3);
    #pragma unroll
    for (int k = 0; k < 2; k++) {
        int fi = wv * 2 + k;
        int mt = fi >> 2, nt = fi & 3;
        int zz = z0 + nt * 2 + ((lane >> 4) & 1);
        #pragma unroll
        for (int s = 0; s < 4; s++) {
            f32x4 v = *(const f32x4*)(red + fi * 1024 + lane * 16 + s * 4);
            v += *(const f32x4*)(red + 8192 + fi * 1024 + lane * 16 + s * 4);
            #pragma unroll
            for (int e = 0; e < 4; e++) {
                int o = mt * 32 + e + 8 * s + 4 * lhi;
                out[((o * OSD + zz) * OSD + yy) * OSD + xx] = v[e];
            }
        }
    }
}

extern "C" void kernel_launch(void* const* d_in, const int* in_sizes, int n_in,
                              void* d_out, int out_size, void* d_ws, size_t ws_size,
                              hipStream_t stream) {
    const float* x      = (const float*)d_in[0];
    const float* weight = (const float*)d_in[1];
    const float* w_sc0  = (const float*)d_in[2];
    const float* w_sc1  = (const float*)d_in[3];
    float* out = (float*)d_out;

    ush* A  = (ush*)d_ws;                               // 514048 ush (incl. zero pad)
    ush* xb = (ush*)((char*)d_ws + (2 << 20));          // 22.5 MB

    aux_kernel<<<NCX + NBA, 256, 0, stream>>>(x, xb, weight, w_sc0, w_sc1, A);
    conv_main<<<1184, 256, 0, stream>>>(A, xb, out);
}